// Round 3
// baseline (130.141 us; speedup 1.0000x reference)
//
#include <hip/hip_runtime.h>

#define HSZ 256
#define WSZ 256
#define NFC 64
#define PLANE (HSZ * WSZ)

typedef __attribute__((ext_vector_type(8))) short short8;
typedef __attribute__((ext_vector_type(4))) float f32x4;

__device__ inline unsigned short f2bf(float f) {
    unsigned u = __builtin_bit_cast(unsigned, f);
    return (unsigned short)((u + 0x7fffu + ((u >> 16) & 1u)) >> 16);   // RTNE
}

// ============================================================================
// Fused dynamic-filter kernel, v4: 16(x) x 8(y) px tile, 256 threads,
// grid (16,32,B) = 1024 blocks -> 4 blocks/CU. No workspace.
//
// v4 vs v3: apply phase reads h DIRECTLY from global (no hs LDS double-buffer,
// no per-cg barriers -> only 2 __syncthreads in the whole kernel). Per thread
// per channel: 1 aligned float4 (own cols) + 2 scalar halo floats per row x 3
// rows; L1 absorbs the 3x ky-overlap (footprint ~1 KB/ch/block). The 8-ch
// loop is barrier-free and independent -> loads pipeline across iterations.
//
// LDS (32688 B -> 4 blocks/CU):
//   [0,     20160) : xs  - i_t tile, 180 sp (10y x 18x) x 56 shorts (48+8 pad)
//   [20160, 28080) : lwT - conv_w transposed [oc][k=kk*48+ic] bf16, stride 440
//   [28080, 32688) : lf  - filters [9][8][16] f32 (separate region: B2 dropped)
// ============================================================================
__global__ __launch_bounds__(256, 4) void fused_dynfilter_v4(
    const float* __restrict__ hbuf,
    const float* __restrict__ i_t,
    const float* __restrict__ wbuf,
    const float* __restrict__ bias,
    float* __restrict__ out)
{
    __shared__ __align__(16) unsigned char smem[32688];
    unsigned short* const xs  = (unsigned short*)smem;            // 180 x 56
    unsigned short* const lwT = (unsigned short*)(smem + 20160);  // 9 x 440
    float* const lf = (float*)(smem + 28080);                     // 9 x 8 x 16

    const int tid = threadIdx.x;

    // XCD-aware bijective block swizzle (total = 512*B, divisible by 8)
    const int lin = blockIdx.x + 16 * (blockIdx.y + 32 * blockIdx.z);
    const int q   = ((int)gridDim.z * 512) >> 3;
    const int nid = (lin & 7) * q + (lin >> 3);
    const int b   = nid >> 9;
    const int rem = nid & 511;
    const int X0  = (rem & 15) * 16;
    const int Y0  = (rem >> 4) * 8;

    const int lane = tid & 63;
    const int l15  = lane & 15;     // A: px col / B,C: oc
    const int kg   = lane >> 4;     // k-subgroup
    const int wv   = tid >> 6;      // wave -> px rows 2wv, 2wv+1

    const float bv = (l15 < 9) ? bias[l15] : 0.f;
    const float* itb = i_t + (size_t)b * 3 * (PLANE * 16);

    // ---- phase 0a: stage shuffled i_t tile (2160 float4 jobs, 9 rounds)
    {
        float4 lreg[9]; int sdst[9];
#pragma unroll
        for (int k = 0; k < 9; ++k) {
            const int v = tid + 256 * k;
            const int sp = v / 12, t = v - sp * 12;          // t = c3*4+fy
            const int c3 = t >> 2, fy = t & 3;
            const int ly = sp / 18, lx = sp - ly * 18;
            const int Y = Y0 - 1 + ly, X = X0 - 1 + lx;
            float4 val = make_float4(0.f, 0.f, 0.f, 0.f);
            if (v < 2160 && (unsigned)Y < HSZ && (unsigned)X < WSZ)
                val = *(const float4*)(itb + ((size_t)c3 * 1024 + (4 * Y + fy)) * 1024 + 4 * X);
            lreg[k] = val;
            sdst[k] = (v < 2160) ? (sp * 56 + t * 4) : -1;
        }
#pragma unroll
        for (int k = 0; k < 9; ++k)
            if (sdst[k] >= 0) {
                ushort4 u{f2bf(lreg[k].x), f2bf(lreg[k].y), f2bf(lreg[k].z), f2bf(lreg[k].w)};
                *(ushort4*)(xs + sdst[k]) = u;
            }
    }

    // ---- phase 0b: stage conv_w -> lwT[oc*440 + kk*48+ic], coalesced f4 loads
    {
        float4 wr[4];
#pragma unroll
        for (int k = 0; k < 4; ++k) {
            const int v = tid + 256 * k;
            wr[k] = (v < 972) ? *(const float4*)(wbuf + (size_t)v * 4)
                              : make_float4(0.f, 0.f, 0.f, 0.f);
        }
#pragma unroll
        for (int k = 0; k < 4; ++k) {
            const int v = tid + 256 * k;
            if (v < 972) {
                const float e[4] = {wr[k].x, wr[k].y, wr[k].z, wr[k].w};
#pragma unroll
                for (int j = 0; j < 4; ++j) {
                    const int n  = v * 4 + j;
                    const int oc = n / 432;
                    const int r  = n - 432 * oc;
                    const int ic = r / 9;
                    const int kk = r - 9 * ic;
                    lwT[oc * 440 + kk * 48 + ic] = f2bf(e[j]);
                }
            }
        }
    }

    __syncthreads();   // B1: xs + lwT ready

    // ---- B-fragments: 14 x ds_read_b128 (k = kb*32 + kg*8 + j, contiguous)
    short8 wf[14];
    {
        const unsigned short* lwb = lwT + l15 * 440 + kg * 8;
#pragma unroll
        for (int kb = 0; kb < 14; ++kb) {
            short8 w = {0, 0, 0, 0, 0, 0, 0, 0};
            if (l15 < 9 && !(kb == 13 && kg >= 2))
                w = *(const short8*)(lwb + kb * 32);
            wf[kb] = w;
        }
    }

    // ---- MFMA: 14 K-blocks x 2 row-tiles (px rows 2wv, 2wv+1)
    f32x4 acc0 = {0.f, 0.f, 0.f, 0.f}, acc1 = acc0;
#pragma unroll
    for (int kb = 0; kb < 14; ++kb) {
        const int k0 = kb * 32 + kg * 8;
        int off = 0;
        if (k0 < 432) {
            const int kk = k0 / 48, ic0 = k0 - 48 * kk;
            const int ky = kk / 3, kx = kk - 3 * ky;
            off = ((2 * wv + ky) * 18 + l15 + kx) * 56 + ic0;    // 16B-aligned
        }
        short8 a0 = *(const short8*)(xs + off);
        short8 a1 = *(const short8*)(xs + off + 1008);           // +1 px row (18*56)
        acc0 = __builtin_amdgcn_mfma_f32_16x16x32_bf16(a0, wf[kb], acc0, 0, 0, 0);
        acc1 = __builtin_amdgcn_mfma_f32_16x16x32_bf16(a1, wf[kb], acc1, 0, 0, 0);
    }

    // ---- filters -> lf (relu + bias); lf is a private region, no hazard
    if (l15 < 9) {
#pragma unroll
        for (int t = 0; t < 2; ++t) {
            const int py = 2 * wv + t;
            const f32x4 A = t ? acc1 : acc0;
#pragma unroll
            for (int r = 0; r < 4; ++r)
                lf[l15 * 128 + py * 16 + (kg * 4 + r)] = fmaxf(A[r] + bv, 0.f);
        }
    }

    __syncthreads();   // B3: lf ready

    // ---- apply phase: barrier-free, direct-global h reads
    const int pq  = tid & 3;          // px group of 4 (x = X0+pq*4..+3)
    const int pyA = (tid >> 2) & 7;   // px row
    const int clo = tid >> 5;         // 0..7: channel offset within group

    // per-pixel filters into registers
    float4 flt[9];
#pragma unroll
    for (int oc = 0; oc < 9; ++oc)
        flt[oc] = *(const float4*)(lf + oc * 128 + pyA * 16 + pq * 4);

    const int col0 = X0 + pq * 4;                 // own 4 output cols
    const int Yc   = Y0 + pyA;
    const bool gl  = (col0 > 0);                  // left halo col col0-1 valid
    const bool gr  = (col0 < WSZ - 4);            // right halo col col0+4 valid

    bool rg[3]; int roff[3];
#pragma unroll
    for (int ky = 0; ky < 3; ++ky) {
        const int Y = Yc - 1 + ky;
        rg[ky]   = ((unsigned)Y < HSZ);
        roff[ky] = Y * WSZ + col0;
    }

    const float* hp0 = hbuf + ((size_t)b * NFC + clo) * PLANE;
    float* outp = out + ((size_t)b * NFC + clo) * PLANE + (size_t)Yc * WSZ + col0;

#pragma unroll 2
    for (int cg = 0; cg < 8; ++cg) {
        const float* p = hp0 + (size_t)cg * 8 * PLANE;

        float a[4] = {0.f, 0.f, 0.f, 0.f};
#pragma unroll
        for (int ky = 0; ky < 3; ++ky) {
            float  sl = (rg[ky] && gl) ? p[roff[ky] - 1] : 0.f;
            float4 fm = rg[ky] ? *(const float4*)(p + roff[ky])
                               : make_float4(0.f, 0.f, 0.f, 0.f);
            float  sr = (rg[ky] && gr) ? p[roff[ky] + 4] : 0.f;
            const float v6[6] = {sl, fm.x, fm.y, fm.z, fm.w, sr};
#pragma unroll
            for (int kx = 0; kx < 3; ++kx)
#pragma unroll
                for (int j = 0; j < 4; ++j)
                    a[j] = fmaf(v6[kx + j], flt[ky * 3 + kx][j], a[j]);
        }

        *(float4*)(outp + (size_t)cg * 8 * PLANE)
            = make_float4(a[0], a[1], a[2], a[3]);
    }
}

extern "C" void kernel_launch(void* const* d_in, const int* in_sizes, int n_in,
                              void* d_out, int out_size, void* d_ws, size_t ws_size,
                              hipStream_t stream) {
    const float* h      = (const float*)d_in[0];
    const float* i_t    = (const float*)d_in[1];
    const float* conv_w = (const float*)d_in[2];
    const float* conv_b = (const float*)d_in[3];
    float* out = (float*)d_out;

    const int B = in_sizes[0] / (NFC * PLANE);
    dim3 grid(WSZ / 16, HSZ / 8, B);
    fused_dynfilter_v4<<<grid, 256, 0, stream>>>(h, i_t, conv_w, conv_b, out);
}

// Round 4
// 116.293 us; speedup vs baseline: 1.1191x; 1.1191x over previous
//
#include <hip/hip_runtime.h>

#define HSZ 256
#define WSZ 256
#define NFC 64
#define PLANE (HSZ * WSZ)

typedef __attribute__((ext_vector_type(8))) short short8;
typedef __attribute__((ext_vector_type(4))) float f32x4;

__device__ inline unsigned short f2bf(float f) {
    unsigned u = __builtin_bit_cast(unsigned, f);
    return (unsigned short)((u + 0x7fffu + ((u >> 16) & 1u)) >> 16);   // RTNE
}

// ============================================================================
// Fused dynamic-filter kernel, v5: 16(x) x 8(y) px tile, 256 threads,
// grid (16,32,B) = 1024 blocks -> 4 blocks/CU. No workspace.
//
// v5 vs v3/v4: apply phase is WAVE-PRIVATE and BARRIER-FREE. Each wave owns
// 16 channels; stages its own 2-channel h tile into its own LDS double
// buffer. Wave64 lockstep + in-order DS pipe + compiler lgkmcnt waits give
// correctness without __syncthreads (only 2 barriers in the whole kernel).
// Loads for iter i+1 issued before compute of iter i (T14 issue-early /
// write-late) -> latency hidden under 36 FMA + TLP; compiler pipelines
// freely across the 8 channel iterations.
//
// LDS 29664 B (5 blocks/CU capacity; grid supplies 4):
//   [0,     17280) : xs  - i_t tile, 180 sp (10y x 18x) x 48 shorts
//   [17280, 25056) : lwT - conv_w transposed [oc][k=kk*48+ic] bf16, stride 432
//   [25056, 29664) : lf  - filters [9][8][16] f32
//   hw (apply) overlays [0, 17920): 4 waves x 2 bufs x (2ch x 10row x 28) f32
//   (xs dead after MFMA, lwT dead after wf gather; hw written only after B3)
// ============================================================================
__global__ __launch_bounds__(256, 4) void fused_dynfilter_v5(
    const float* __restrict__ hbuf,
    const float* __restrict__ i_t,
    const float* __restrict__ wbuf,
    const float* __restrict__ bias,
    float* __restrict__ out)
{
    __shared__ __align__(16) unsigned char smem[29664];
    unsigned short* const xs  = (unsigned short*)smem;            // 180 x 48
    unsigned short* const lwT = (unsigned short*)(smem + 17280);  // 9 x 432
    float* const lf = (float*)(smem + 25056);                     // 9 x 8 x 16
    float* const hw = (float*)smem;                               // waves x 1120

    const int tid = threadIdx.x;

    // XCD-aware bijective block swizzle (total = 512*B, divisible by 8)
    const int lin = blockIdx.x + 16 * (blockIdx.y + 32 * blockIdx.z);
    const int q   = ((int)gridDim.z * 512) >> 3;
    const int nid = (lin & 7) * q + (lin >> 3);
    const int b   = nid >> 9;
    const int rem = nid & 511;
    const int X0  = (rem & 15) * 16;
    const int Y0  = (rem >> 4) * 8;

    const int lane = tid & 63;
    const int l15  = lane & 15;     // A: px col / B,C: oc
    const int kg   = lane >> 4;     // k-subgroup
    const int wv   = tid >> 6;      // wave id

    const float bv = (l15 < 9) ? bias[l15] : 0.f;
    const float* itb = i_t + (size_t)b * 3 * (PLANE * 16);

    // ---- phase 0a: stage shuffled i_t tile (2160 float4 jobs, 9 rounds)
    {
        float4 lreg[9]; int sdst[9];
#pragma unroll
        for (int k = 0; k < 9; ++k) {
            const int v = tid + 256 * k;
            const int sp = v / 12, t = v - sp * 12;          // t = c3*4+fy
            const int c3 = t >> 2, fy = t & 3;
            const int ly = sp / 18, lx = sp - ly * 18;
            const int Y = Y0 - 1 + ly, X = X0 - 1 + lx;
            float4 val = make_float4(0.f, 0.f, 0.f, 0.f);
            if (v < 2160 && (unsigned)Y < HSZ && (unsigned)X < WSZ)
                val = *(const float4*)(itb + ((size_t)c3 * 1024 + (4 * Y + fy)) * 1024 + 4 * X);
            lreg[k] = val;
            sdst[k] = (v < 2160) ? (sp * 48 + t * 4) : -1;
        }
#pragma unroll
        for (int k = 0; k < 9; ++k)
            if (sdst[k] >= 0) {
                ushort4 u{f2bf(lreg[k].x), f2bf(lreg[k].y), f2bf(lreg[k].z), f2bf(lreg[k].w)};
                *(ushort4*)(xs + sdst[k]) = u;
            }
    }

    // ---- phase 0b: stage conv_w -> lwT[oc*432 + kk*48+ic], coalesced f4 loads
    {
        float4 wr[4];
#pragma unroll
        for (int k = 0; k < 4; ++k) {
            const int v = tid + 256 * k;
            wr[k] = (v < 972) ? *(const float4*)(wbuf + (size_t)v * 4)
                              : make_float4(0.f, 0.f, 0.f, 0.f);
        }
#pragma unroll
        for (int k = 0; k < 4; ++k) {
            const int v = tid + 256 * k;
            if (v < 972) {
                const float e[4] = {wr[k].x, wr[k].y, wr[k].z, wr[k].w};
#pragma unroll
                for (int j = 0; j < 4; ++j) {
                    const int n  = v * 4 + j;
                    const int oc = n / 432;
                    const int r  = n - 432 * oc;
                    const int ic = r / 9;
                    const int kk = r - 9 * ic;
                    lwT[oc * 432 + kk * 48 + ic] = f2bf(e[j]);
                }
            }
        }
    }

    __syncthreads();   // B1: xs + lwT ready

    // ---- B-fragments: 14 x ds_read_b128 (k = kb*32 + kg*8 + j, contiguous)
    short8 wf[14];
    {
        const unsigned short* lwb = lwT + l15 * 432 + kg * 8;
#pragma unroll
        for (int kb = 0; kb < 14; ++kb) {
            short8 w = {0, 0, 0, 0, 0, 0, 0, 0};
            if (l15 < 9 && !(kb == 13 && kg >= 2))
                w = *(const short8*)(lwb + kb * 32);
            wf[kb] = w;
        }
    }

    // ---- MFMA: 14 K-blocks x 2 row-tiles (px rows 2wv, 2wv+1)
    f32x4 acc0 = {0.f, 0.f, 0.f, 0.f}, acc1 = acc0;
#pragma unroll
    for (int kb = 0; kb < 14; ++kb) {
        const int k0 = kb * 32 + kg * 8;
        int off = 0;
        if (k0 < 432) {
            const int kk = k0 / 48, ic0 = k0 - 48 * kk;
            const int ky = kk / 3, kx = kk - 3 * ky;
            off = ((2 * wv + ky) * 18 + l15 + kx) * 48 + ic0;    // 16B-aligned
        }
        short8 a0 = *(const short8*)(xs + off);
        short8 a1 = *(const short8*)(xs + off + 864);            // +1 px row (18*48)
        acc0 = __builtin_amdgcn_mfma_f32_16x16x32_bf16(a0, wf[kb], acc0, 0, 0, 0);
        acc1 = __builtin_amdgcn_mfma_f32_16x16x32_bf16(a1, wf[kb], acc1, 0, 0, 0);
    }

    // ---- apply-phase lane mapping (wave-private): lane = c01*32 + row*4 + pq
    const int pq  = lane & 3;          // px quad (x = X0+pq*4..+3)
    const int row = (lane >> 2) & 7;   // px row
    const int c01 = lane >> 5;         // channel within staged pair
    float* const hwv = hw + wv * 1120; // this wave's 2 bufs x 560 floats

    // h staging job: 120 float4 jobs per iter (2 ch x 10 rows x 6 quads)
    auto load_h = [&](int it, float4 (&r)[2], int (&d)[2]) {
        const float* hp0 = hbuf + ((size_t)b * NFC + wv * 16 + it * 2) * PLANE;
#pragma unroll
        for (int k = 0; k < 2; ++k) {
            const int j = lane + 64 * k;
            float4 val = make_float4(0.f, 0.f, 0.f, 0.f);
            int dd = -1;
            if (j < 120) {
                const int cc  = j / 60, rr = j - 60 * cc;
                const int rw  = rr / 6, xq = rr - 6 * rw;
                const int Y   = Y0 - 1 + rw;
                const int X4  = X0 - 4 + xq * 4;
                if ((unsigned)Y < HSZ && (unsigned)X4 < WSZ)
                    val = *(const float4*)(hp0 + (size_t)cc * PLANE + (size_t)Y * WSZ + X4);
                dd = cc * 280 + rw * 28 + xq * 4;    // 16B-aligned
            }
            r[k] = val; d[k] = dd;
        }
    };

    // issue iter-0 h loads (in flight across lf-write + barrier)
    float4 pre[2]; int pd[2];
    load_h(0, pre, pd);

    // ---- filters -> lf (relu + bias)
    if (l15 < 9) {
#pragma unroll
        for (int t = 0; t < 2; ++t) {
            const int py = 2 * wv + t;
            const f32x4 A = t ? acc1 : acc0;
#pragma unroll
            for (int r = 0; r < 4; ++r)
                lf[l15 * 128 + py * 16 + (kg * 4 + r)] = fmaxf(A[r] + bv, 0.f);
        }
    }

    __syncthreads();   // B3: lf ready; xs/lwT dead -> hw may be written

    // per-pixel filters into registers
    float4 flt[9];
#pragma unroll
    for (int oc = 0; oc < 9; ++oc)
        flt[oc] = *(const float4*)(lf + oc * 128 + row * 16 + pq * 4);

    // write iter-0 tile into buf0 (wave-private; lgkmcnt orders vs reads)
#pragma unroll
    for (int k = 0; k < 2; ++k)
        if (pd[k] >= 0) *(float4*)(hwv + pd[k]) = pre[k];

    float* outp = out + ((size_t)b * NFC + wv * 16 + c01) * PLANE
                      + (size_t)(Y0 + row) * WSZ + X0 + pq * 4;

    // ---- 8 wave-private channel iterations, zero barriers
#pragma unroll
    for (int it = 0; it < 8; ++it) {
        const int buf = it & 1;

        float4 nr[2]; int nd[2];
        if (it < 7) load_h(it + 1, nr, nd);          // issue-early

        const float* pl = hwv + buf * 560 + c01 * 280;
        float a[4] = {0.f, 0.f, 0.f, 0.f};
#pragma unroll
        for (int ky = 0; ky < 3; ++ky) {
            const float* rp = pl + (row + ky) * 28 + pq * 4;   // col 0 = X0-4
            const float4 w0 = *(const float4*)rp;
            const float4 w1 = *(const float4*)(rp + 4);
            const float  w8 = rp[8];
            const float vs[9] = {w0.x, w0.y, w0.z, w0.w, w1.x, w1.y, w1.z, w1.w, w8};
#pragma unroll
            for (int kx = 0; kx < 3; ++kx)
#pragma unroll
                for (int j = 0; j < 4; ++j)
                    a[j] = fmaf(vs[3 + kx + j], flt[ky * 3 + kx][j], a[j]);
        }

        *(float4*)(outp + (size_t)it * 2 * PLANE)
            = make_float4(a[0], a[1], a[2], a[3]);

        if (it < 7) {                                 // write-late
            float* hb = hwv + (buf ^ 1) * 560;
#pragma unroll
            for (int k = 0; k < 2; ++k)
                if (nd[k] >= 0) *(float4*)(hb + nd[k]) = nr[k];
        }
    }
}

extern "C" void kernel_launch(void* const* d_in, const int* in_sizes, int n_in,
                              void* d_out, int out_size, void* d_ws, size_t ws_size,
                              hipStream_t stream) {
    const float* h      = (const float*)d_in[0];
    const float* i_t    = (const float*)d_in[1];
    const float* conv_w = (const float*)d_in[2];
    const float* conv_b = (const float*)d_in[3];
    float* out = (float*)d_out;

    const int B = in_sizes[0] / (NFC * PLANE);
    dim3 grid(WSZ / 16, HSZ / 8, B);
    fused_dynfilter_v5<<<grid, 256, 0, stream>>>(h, i_t, conv_w, conv_b, out);
}